// Round 6
// baseline (316.898 us; speedup 1.0000x reference)
//
#include <hip/hip_runtime.h>
#include <math.h>

#define S_LEN 2048
#define B_N   4096
#define CPB   8             // chains per block
#define NBLK  (S_LEN / 8)   // 256 eight-step blocks
#define SBK   8             // kk-blocks per superblock (barrier period = 64 steps)
#define NSB   (NBLK / SBK)  // 32 superblocks

__device__ __forceinline__ float hw_exp2(float x) { return __builtin_amdgcn_exp2f(x); }
__device__ __forceinline__ float hw_rcp(float x)  { return __builtin_amdgcn_rcpf(x); }

// DPP ctrls (within 16-lane rows; all involutions, no direction ambiguity):
//   0x55*K : quad_perm broadcast lane K of each quad
//   0x1B   : quad_perm [3,2,1,0]  == lane ^ 3
//   0x128  : row_ror:8            == lane ^ 8
//   0x141  : row_half_mirror      == lane ^ 7
template<int CTRL>
__device__ __forceinline__ float dpp_mov(float v) {
    return __int_as_float(__builtin_amdgcn_mov_dpp(__float_as_int(v), CTRL, 0xF, 0xF, false));
}
template<int K>
__device__ __forceinline__ float quad_bcast(float v) { return dpp_mov<K * 0x55>(v); }

__global__ __launch_bounds__(256) void lstm2_kernel(
    const float* __restrict__ X,
    const float* __restrict__ Wih0, const float* __restrict__ Whh0,
    const float* __restrict__ bih0, const float* __restrict__ bhh0,
    const float* __restrict__ Wih1, const float* __restrict__ Whh1,
    const float* __restrict__ bih1, const float* __restrict__ bhh1,
    const float* __restrict__ Wout, const float* __restrict__ bOut,
    float* __restrict__ Y)
{
    const int tix  = threadIdx.x;
    const int role = tix >> 7;            // 0 = layer0 waves (0,1), 1 = layer1 waves (2,3)
    const int cpos = (tix & 127) >> 4;    // chain slot within block (0..7)
    const int l16  = tix & 15;
    const int m    = l16 >> 2;            // hidden unit (quad index)
    const int g    = l16 & 3;             // gate: 0=i 1=f 2=g 3=o
    const int j    = g * 4 + m;           // row in the (4H) stacked weight layout
    const int b    = blockIdx.x * CPB + cpos;

    // h1 handoff ring: [superbuf][kk2][chain][36 floats]
    //   per chain: 8 steps x 4 units (32) + 4 pad -> 144B stride (bank-conflict-free)
    __shared__ float ring[2][SBK][CPB][36];

    const float LOG2E = 1.4426950408889634f;
    const float TWO_LOG2E = 2.8853900817779268f;
    const bool  is_tanh = (g == 2);
    // sigmoid rows: z = -log2e*pre;  sigmoid = rcp(1+exp2(z))
    // tanh rows:    z = +2log2e*pre; tanh    = 1 - 2*rcp(1+exp2(z))
    const float s  = is_tanh ? (2.0f * LOG2E) : (-LOG2E);
    const float ka = is_tanh ? -2.0f : 1.0f;
    const float kb = is_tanh ?  1.0f : 0.0f;

    // role-specific weights (prescaled)
    float a0 = 0.f, bias = 0.f, U[4], Wi[4], wop[4], bo = 0.f;
    if (role == 0) {
        a0   = Wih0[j] * s;
        bias = (bih0[j] + bhh0[j]) * s;
        #pragma unroll
        for (int d = 0; d < 4; ++d) U[d] = Whh0[j * 4 + (m ^ d)] * s;
        #pragma unroll
        for (int d = 0; d < 4; ++d) { Wi[d] = 0.f; wop[d] = 0.f; }
    } else {
        bias = (bih1[j] + bhh1[j]) * s;
        #pragma unroll
        for (int e = 0; e < 4; ++e) Wi[e] = Wih1[j * 4 + e] * s;   // canonical order
        #pragma unroll
        for (int d = 0; d < 4; ++d) U[d] = Whh1[j * 4 + (m ^ d)] * s;
        #pragma unroll
        for (int d = 0; d < 4; ++d) wop[d] = Wout[m ^ d];
        bo = bOut[0];
    }

    // per-lane recurrent state: v[d] = h[m^d] broadcast vector, c = unit's cell
    float c = 0.f, v0 = 0.f, v1 = 0.f, v2 = 0.f, v3 = 0.f;

    // gate tail: z -> activation -> gather -> c update -> h -> spread
    auto gate_tail = [&](float z) {
        float r   = hw_rcp(1.0f + hw_exp2(z));
        float act = fmaf(ka, r, kb);
        float iv = quad_bcast<0>(act), fv = quad_bcast<1>(act);
        float gv = quad_bcast<2>(act), ov = quad_bcast<3>(act);
        c = fmaf(fv, c, iv * gv);
        float e2 = hw_exp2(c * TWO_LOG2E);
        float rc = hw_rcp(1.0f + e2);
        float o2 = ov + ov;                    // off critical path
        float h  = fmaf(-o2, rc, ov);          // h = o * (1 - 2*rc) = o*tanh(c)
        v0 = h;
        v2 = dpp_mov<0x128>(h);                // xor8 (1 DPP, ready early)
        v1 = dpp_mov<0x1B>(dpp_mov<0x141>(h)); // xor7 then xor3 => xor4
        v3 = dpp_mov<0x128>(v1);               // xor12
    };

    float xbuf[8];
    if (role == 0) {
        #pragma unroll
        for (int u = 0; u < 8; ++u) xbuf[u] = X[u * B_N + b];
    }
    float ybuf[8];

    // Superblock pipeline: L0 fills ring[sb&1] with steps [sb*64, sb*64+64);
    // L1 consumes ring[(sb-1)&1]. One barrier per 64 steps.
    for (int sb = 0; sb <= NSB; ++sb) {
        if (role == 0) {
            if (sb < NSB) {
                #pragma unroll 1
                for (int k2 = 0; k2 < SBK; ++k2) {
                    const int t0 = (sb * SBK + k2) * 8;
                    float* wr = &ring[sb & 1][k2][cpos][0];
                    #pragma unroll
                    for (int u = 0; u < 8; ++u) {
                        float x = xbuf[u];
                        int tn = t0 + 8 + u; if (tn > S_LEN - 1) tn = S_LEN - 1;
                        xbuf[u] = X[tn * B_N + b];          // prefetch next block
                        // z ordered by operand availability (v0 first, v1/v3 last)
                        float z = fmaf(x, a0, bias);
                        z = fmaf(U[0], v0, z);
                        z = fmaf(U[2], v2, z);
                        z = fmaf(U[1], v1, z);
                        z = fmaf(U[3], v3, z);
                        gate_tail(z);
                        // lane (g=0,m=0) holds (h0,h1,h2,h3) = (v0,v1,v2,v3)
                        if (l16 == 0)
                            *(float4*)&wr[u * 4] = make_float4(v0, v1, v2, v3);
                    }
                }
            }
        } else {
            if (sb >= 1) {
                #pragma unroll 1
                for (int k2 = 0; k2 < SBK; ++k2) {
                    const int t0 = ((sb - 1) * SBK + k2) * 8;
                    const float4* rd = (const float4*)&ring[(sb - 1) & 1][k2][cpos][0];
                    float4 n[8];
                    #pragma unroll
                    for (int u = 0; u < 8; ++u) n[u] = rd[u];   // broadcast b128 reads
                    #pragma unroll
                    for (int u = 0; u < 8; ++u) {
                        float z = fmaf(Wi[0], n[u].x, bias);
                        z = fmaf(Wi[1], n[u].y, z);
                        z = fmaf(Wi[2], n[u].z, z);
                        z = fmaf(Wi[3], n[u].w, z);
                        z = fmaf(U[0], v0, z);
                        z = fmaf(U[2], v2, z);
                        z = fmaf(U[1], v1, z);
                        z = fmaf(U[3], v3, z);
                        gate_tail(z);
                        float y = fmaf(wop[0], v0, bo);
                        y = fmaf(wop[1], v1, y);
                        y = fmaf(wop[2], v2, y);
                        y = fmaf(wop[3], v3, y);
                        ybuf[u] = y;
                    }
                    if (l16 == 0) {
                        #pragma unroll
                        for (int u = 0; u < 8; ++u) Y[(t0 + u) * B_N + b] = ybuf[u];
                    }
                }
            }
        }
        __syncthreads();
    }
}

extern "C" void kernel_launch(void* const* d_in, const int* in_sizes, int n_in,
                              void* d_out, int out_size, void* d_ws, size_t ws_size,
                              hipStream_t stream) {
    const float* X    = (const float*)d_in[0];
    const float* Wih0 = (const float*)d_in[1];
    const float* Whh0 = (const float*)d_in[2];
    const float* bih0 = (const float*)d_in[3];
    const float* bhh0 = (const float*)d_in[4];
    const float* Wih1 = (const float*)d_in[5];
    const float* Whh1 = (const float*)d_in[6];
    const float* bih1 = (const float*)d_in[7];
    const float* bhh1 = (const float*)d_in[8];
    const float* Wout = (const float*)d_in[9];
    const float* bOut = (const float*)d_in[10];
    float* Y = (float*)d_out;

    // 512 blocks x 256 threads: 8 chains/block, waves 0-1 = layer0, waves 2-3
    // = layer1. 2048 waves = 2 waves/SIMD; 2 blocks/CU. Barrier every 64 steps.
    dim3 grid(B_N / CPB), block(256);
    hipLaunchKernelGGL(lstm2_kernel, grid, block, 0, stream,
                       X, Wih0, Whh0, bih0, bhh0, Wih1, Whh1, bih1, bhh1, Wout, bOut, Y);
}